// Round 4
// baseline (31.313 us; speedup 1.0000x reference)
//
#include <hip/hip_runtime.h>

// Differentiable histogram: img (128*512*512 f32) -> 256-bin linear-interp hist.
// s = x*255; mass (1-d) to bin b, d to bin b+1; bin 256 dropped.
//
// R4 design:
//  - ONE ds_add_u64 per element instead of two ds_add_u32:
//      pack (count, sum_d) as (1<<32 | d16) into u64 counter of bin b.
//      h[b] = c[b] - g[b]/2^16 + g[b-1]/2^16   (prefix-difference, per block).
//    Halves atomic issues + address calc; same LDS bank-cycle count.
//  - Branchless: out-of-range elements add 0 to bin 0 (no exec-mask churn).
//  - 16 u64 copies, transposed lh[bin*16 + (lane&15)] (32 KB -> 4 blocks/CU).
//    Overflow: worst case per block 32768 elems * 2^16 = 2^31 < 2^32. Safe.
//  - Per-block fp32 partials to d_ws ([bin][block]); reduce kernel sums them.

#define NBIN   256
#define NCOPY  16
#define BLK1   512
#define GRID1  1024
#define BLK2   256

__global__ __launch_bounds__(BLK1) void diffhist_partial(
    const float* __restrict__ img, float* __restrict__ partial, long long n)
{
    __shared__ unsigned long long lh[NBIN * NCOPY];   // 32,768 B
    __shared__ unsigned long long tot[NBIN];          //  2,048 B

    const int tid = threadIdx.x;
    const int c   = tid & (NCOPY - 1);

    for (int i = tid; i < NBIN * NCOPY; i += BLK1) lh[i] = 0ull;
    __syncthreads();

    const long long gtid = (long long)blockIdx.x * BLK1 + tid;
    const long long gsz  = (long long)gridDim.x * BLK1;
    const long long n4   = n >> 2;
    const float4* __restrict__ in4 = (const float4*)img;

    auto proc = [&](float x) {
        const bool keep = (x >= 0.0f) & (x <= 1.0f);
        float s = x * 255.0f;
        float f = floorf(s);
        float d = s - f;
        int   b = (int)f;
        b = keep ? b : 0;
        unsigned d16 = (unsigned)(d * 65536.0f + 0.5f);     // [0, 65536]
        unsigned long long inc =
            keep ? ((1ull << 32) | (unsigned long long)d16) : 0ull;
        atomicAdd(&lh[b * NCOPY + c], inc);                  // native ds_add_u64
    };

    long long i = gtid;
    for (; i + gsz < n4; i += 2 * gsz) {                     // 2x float4 / iter
        float4 a = in4[i];
        float4 b4 = in4[i + gsz];
        proc(a.x);  proc(a.y);  proc(a.z);  proc(a.w);
        proc(b4.x); proc(b4.y); proc(b4.z); proc(b4.w);
    }
    for (; i < n4; i += gsz) {
        float4 a = in4[i];
        proc(a.x); proc(a.y); proc(a.z); proc(a.w);
    }
    for (long long j = (n4 << 2) + gtid; j < n; j += gsz)    // n % 4 tail
        proc(img[j]);

    __syncthreads();

    // Sum the 16 copies per bin (rotated start: conflict-light), then
    // finalize h_block[b] = c[b] - (g[b] - g[b-1]) / 2^16 locally.
    for (int b = tid; b < NBIN; b += BLK1) {
        unsigned long long s = 0ull;
        #pragma unroll
        for (int k = 0; k < NCOPY; ++k)
            s += lh[b * NCOPY + ((b + k) & (NCOPY - 1))];
        tot[b] = s;
    }
    __syncthreads();

    if (tid < NBIN) {
        unsigned long long t = tot[tid];
        double cb = (double)(t >> 32);
        double gb = (double)(t & 0xffffffffull);
        double gp = (tid > 0) ? (double)(tot[tid - 1] & 0xffffffffull) : 0.0;
        partial[(long long)tid * gridDim.x + blockIdx.x] =
            (float)(cb - (gb - gp) * (1.0 / 65536.0));
    }
}

__global__ __launch_bounds__(BLK2) void diffhist_reduce(
    const float* __restrict__ partial, float* __restrict__ out, int G)
{
    const int b = blockIdx.x;                 // bin
    const float* __restrict__ p = partial + (long long)b * G;

    float s = 0.0f;
    for (int i = threadIdx.x; i < G; i += BLK2) s += p[i];

    #pragma unroll
    for (int off = 32; off > 0; off >>= 1) s += __shfl_down(s, off, 64);

    __shared__ float wsum[BLK2 / 64];
    const int wave = threadIdx.x >> 6;
    const int lane = threadIdx.x & 63;
    if (lane == 0) wsum[wave] = s;
    __syncthreads();
    if (threadIdx.x == 0) {
        float tot = 0.0f;
        #pragma unroll
        for (int w = 0; w < BLK2 / 64; ++w) tot += wsum[w];
        out[b] = tot;
    }
}

extern "C" void kernel_launch(void* const* d_in, const int* in_sizes, int n_in,
                              void* d_out, int out_size, void* d_ws, size_t ws_size,
                              hipStream_t stream) {
    const float* img = (const float*)d_in[0];
    float* out = (float*)d_out;
    float* partial = (float*)d_ws;
    const long long n = (long long)in_sizes[0];

    int G = GRID1;
    size_t need = (size_t)G * NBIN * sizeof(float);
    if (ws_size < need) {
        G = (int)(ws_size / ((size_t)NBIN * sizeof(float)));
        if (G < 1) G = 1;
    }

    diffhist_partial<<<G, BLK1, 0, stream>>>(img, partial, n);
    // d_out fully overwritten by reduce kernel (no memset needed).
    diffhist_reduce<<<NBIN, BLK2, 0, stream>>>(partial, out, G);
}